// Round 3
// baseline (663.896 us; speedup 1.0000x reference)
//
#include <hip/hip_runtime.h>
#include <hip/hip_bf16.h>

// GCN 2-layer. msg[s] = dinv[s] * (x@W)[s] stored in bf16 (dinv folded at GEMM epilogue).
// out[v] = dinv[v] * (sum_{e:dst=v} msg[src] + msg[v]) + b ; layer1 relu.
// CSR build: bucketed 2-phase counting sort (bucket = dst>>8).
// W pre-split once per launch into transposed bf16 hi/lo [col][k].
// GEMMs: MFMA 16x16x32 bf16, 2-term split (~fp32 accuracy), x tile in LDS.
// R8 lesson: nt stores on sub-sector scattered stores cause 4x write amplification. Only
//   use nt on >=64B-aligned contiguous stores. nt loads on one-touch streams: neutral, kept.
// R9 lesson: deeper MLP changed nothing (65.7us, 3.8TB/s, FETCH 193MB identical) =>
//   agg1 is traffic-bound, not latency-bound. FETCH ~= 8 XCDs x 25.6MB msg1 = the
//   per-XCD compulsory floor for random gathers from private L2s.
// R10: feature-chunked XCD-pinned aggregation (layer 1). msg1 stored chunk-major:
//   8 arrays [N][16 feats] of 3.2MB. Block's chunk = blockIdx&7 -> under empirical
//   round-robin blockIdx->XCD mapping, each XCD gathers from a 3.2MB L2-RESIDENT array.
//   Mapping is a perf-only assumption; coverage/correctness hold regardless.
//   Cost: csr/deg/rs/dinv read once per chunk (csr fetch x8 = 51MB streamed).

#define BSH 8
#define BCHUNK 8192

typedef __attribute__((ext_vector_type(8))) short short8;
typedef __attribute__((ext_vector_type(4))) float float4v;
typedef __attribute__((ext_vector_type(2))) float float2v;

__device__ __forceinline__ float bf_lo(unsigned u) { return __uint_as_float(u << 16); }
__device__ __forceinline__ float bf_hi(unsigned u) { return __uint_as_float(u & 0xffff0000u); }
__device__ __forceinline__ float bf2f(unsigned short h) {
    return __uint_as_float((unsigned)h << 16);
}
__device__ __forceinline__ unsigned short f2bf(float f) {
    unsigned u = __float_as_uint(f);
    u += 0x7fff + ((u >> 16) & 1);  // round-to-nearest-even
    return (unsigned short)(u >> 16);
}
__device__ __forceinline__ void acc8(float* acc, uint4 m) {
    acc[0] += bf_lo(m.x); acc[1] += bf_hi(m.x);
    acc[2] += bf_lo(m.y); acc[3] += bf_hi(m.y);
    acc[4] += bf_lo(m.z); acc[5] += bf_hi(m.z);
    acc[6] += bf_lo(m.w); acc[7] += bf_hi(m.w);
}

// ---------------- CSR build ----------------

__global__ void k_bucket_hist(const int* __restrict__ dst, int* __restrict__ bhist,
                              int E, int nb) {
    __shared__ int h[512];
    int t = threadIdx.x;
    for (int j = t; j < nb; j += blockDim.x) h[j] = 0;
    __syncthreads();
    int i = blockIdx.x * blockDim.x + t;
    int stride = gridDim.x * blockDim.x;
    for (; i < E; i += stride) atomicAdd(&h[dst[i] >> BSH], 1);
    __syncthreads();
    for (int j = t; j < nb; j += blockDim.x) {
        int c = h[j];
        if (c) atomicAdd(&bhist[j], c);
    }
}

__global__ void k_bucket_scan(const int* __restrict__ bhist, int* __restrict__ bbase,
                              int* __restrict__ bwcur, int nb, int E) {
    __shared__ int s[512];
    int t = threadIdx.x;
    int v = (t < nb) ? bhist[t] : 0;
    s[t] = v;
    __syncthreads();
    for (int off = 1; off < 512; off <<= 1) {
        int add = (t >= off) ? s[t - off] : 0;
        __syncthreads();
        s[t] += add;
        __syncthreads();
    }
    if (t < nb) {
        int excl = s[t] - v;
        bbase[t] = excl;
        bwcur[t] = excl;
    }
    if (t == 0) bbase[nb] = E;
}

__global__ void k_bucket_scatter(const int* __restrict__ src, const int* __restrict__ dst,
                                 int* __restrict__ bwcur,
                                 unsigned long long* __restrict__ tmp, int E, int nb) {
    __shared__ int lh[512];
    __shared__ int lb[512];
    int t = threadIdx.x;
    for (int j = t; j < nb; j += 256) lh[j] = 0;
    __syncthreads();
    int e0 = blockIdx.x * BCHUNK;
    int e1 = min(E, e0 + BCHUNK);
    for (int e = e0 + t; e < e1; e += 256) atomicAdd(&lh[dst[e] >> BSH], 1);
    __syncthreads();
    for (int j = t; j < nb; j += 256) {
        int c = lh[j];
        lb[j] = c ? atomicAdd(&bwcur[j], c) : 0;
        lh[j] = 0;
    }
    __syncthreads();
    for (int e = e0 + t; e < e1; e += 256) {
        int d = dst[e];
        int b = d >> BSH;
        int o = atomicAdd(&lh[b], 1);
        tmp[lb[b] + o] = ((unsigned long long)(unsigned)d << 32) | (unsigned)src[e];
    }
}

__global__ void k_bucket_finalize(const unsigned long long* __restrict__ tmp,
                                  const int* __restrict__ bbase,
                                  int* __restrict__ deg, float* __restrict__ dinv,
                                  int* __restrict__ rs, int* __restrict__ csr, int N) {
    __shared__ int cnt[256];
    __shared__ int sc[256];
    int b = blockIdx.x;
    int t = threadIdx.x;
    int e0 = bbase[b], e1 = bbase[b + 1];
    cnt[t] = 0;
    __syncthreads();
    for (int e = e0 + t; e < e1; e += 256) {
        int d = (int)(tmp[e] >> 32);
        atomicAdd(&cnt[d & 255], 1);
    }
    __syncthreads();
    int c = cnt[t];
    sc[t] = c;
    __syncthreads();
    for (int off = 1; off < 256; off <<= 1) {
        int add = (t >= off) ? sc[t - off] : 0;
        __syncthreads();
        sc[t] += add;
        __syncthreads();
    }
    int excl = sc[t] - c;
    __syncthreads();
    sc[t] = excl;
    int node = (b << BSH) + t;
    if (node < N) {
        deg[node] = c;
        dinv[node] = rsqrtf((float)(c + 1));
        rs[node] = e0 + excl;
    }
    cnt[t] = 0;
    __syncthreads();
    for (int e = e0 + t; e < e1; e += 256) {
        unsigned long long p = tmp[e];
        int j = ((int)(p >> 32)) & 255;
        int o = atomicAdd(&cnt[j], 1);
        csr[e0 + sc[j] + o] = (int)(p & 0xffffffffu);
    }
}

// ---------------- W pre-split: Wt_h/Wt_l[col][k] bf16, cols >= DOUT zeroed ----------------
__global__ void k_prep_w(const float* __restrict__ W, unsigned short* __restrict__ Wth,
                         unsigned short* __restrict__ Wtl, int DOUT, int COLS) {
    int i = blockIdx.x * blockDim.x + threadIdx.x;
    if (i >= COLS * 128) return;
    int col = i % COLS;
    int k = i / COLS;
    float w = (col < DOUT) ? W[k * DOUT + col] : 0.f;
    unsigned short h = f2bf(w);
    Wth[(size_t)col * 128 + k] = h;
    Wtl[(size_t)col * 128 + k] = f2bf(w - bf2f(h));
}

// ---------------- MFMA GEMM (split-bf16, ~fp32 accuracy) ----------------
// Y[r,c] = bf16(dinv[r] * (X@W)[r,c]). Block: 4 waves, 64 rows, K=128.
// CM=true: chunk-major output Y[((col>>4)*n + row)*16 + (col&15)] (for XCD-pinned agg).
template <int DOUT, int OSTRIDE, int NT, bool CM>
__global__ __launch_bounds__(256, 3) void k_gemm_mfma(
        const float* __restrict__ X, const unsigned short* __restrict__ Wth,
        const unsigned short* __restrict__ Wtl,
        const float* __restrict__ dinv, unsigned short* __restrict__ Y, int n) {
    __shared__ short xs_h[64][136];
    __shared__ short xs_l[64][136];
    int t = threadIdx.x;
    int lane = t & 63, wave = t >> 6;
    int m16 = lane & 15, quad = lane >> 4;
    int r0 = blockIdx.x * 64;

    short8 bh[2][4], bl[2][4];
    int nt0 = wave, nt1 = wave + 4;
#pragma unroll
    for (int i = 0; i < 2; i++) {
        int nt = i ? nt1 : nt0;
        if (nt >= NT) continue;
        int col = nt * 16 + m16;  // < NT*16 <= COLS (Wt padded)
#pragma unroll
        for (int kc = 0; kc < 4; kc++) {
            bh[i][kc] = *(const short8*)&Wth[(size_t)col * 128 + kc * 32 + quad * 8];
            bl[i][kc] = *(const short8*)&Wtl[(size_t)col * 128 + kc * 32 + quad * 8];
        }
    }

    for (int p = t; p < 64 * 64; p += 256) {
        int row = p >> 6;
        int kk = p & 63;
        int gr = r0 + row;
        if (gr >= n) gr = n - 1;
        float2v xv = __builtin_nontemporal_load(
            (const float2v*)(X + (size_t)gr * 128 + 2 * kk));
        unsigned short h0 = f2bf(xv.x), h1 = f2bf(xv.y);
        unsigned short l0 = f2bf(xv.x - bf2f(h0)), l1 = f2bf(xv.y - bf2f(h1));
        *(unsigned*)&xs_h[row][2 * kk] = (unsigned)h0 | ((unsigned)h1 << 16);
        *(unsigned*)&xs_l[row][2 * kk] = (unsigned)l0 | ((unsigned)l1 << 16);
    }
    __syncthreads();

    float4v acc[2][4];
#pragma unroll
    for (int i = 0; i < 2; i++)
#pragma unroll
        for (int ms = 0; ms < 4; ms++) acc[i][ms] = (float4v){0.f, 0.f, 0.f, 0.f};

#pragma unroll
    for (int kc = 0; kc < 4; kc++) {
#pragma unroll
        for (int ms = 0; ms < 4; ms++) {
            short8 ah = *(short8*)&xs_h[ms * 16 + m16][kc * 32 + quad * 8];
            short8 al = *(short8*)&xs_l[ms * 16 + m16][kc * 32 + quad * 8];
#pragma unroll
            for (int i = 0; i < 2; i++) {
                int nt = i ? nt1 : nt0;
                if (nt >= NT) continue;
                acc[i][ms] = __builtin_amdgcn_mfma_f32_16x16x32_bf16(ah, bh[i][kc], acc[i][ms], 0, 0, 0);
                acc[i][ms] = __builtin_amdgcn_mfma_f32_16x16x32_bf16(al, bh[i][kc], acc[i][ms], 0, 0, 0);
                acc[i][ms] = __builtin_amdgcn_mfma_f32_16x16x32_bf16(ah, bl[i][kc], acc[i][ms], 0, 0, 0);
            }
        }
    }

#pragma unroll
    for (int i = 0; i < 2; i++) {
        int nt = i ? nt1 : nt0;
        if (nt >= NT) continue;
        int col = nt * 16 + m16;
        if (col >= OSTRIDE) continue;
#pragma unroll
        for (int ms = 0; ms < 4; ms++) {
#pragma unroll
            for (int r = 0; r < 4; r++) {
                int row = r0 + ms * 16 + quad * 4 + r;
                if (row < n) {
                    float val = (col < DOUT) ? acc[i][ms][r] * dinv[row] : 0.f;
                    if (CM)
                        Y[((size_t)nt * n + row) * 16 + m16] = f2bf(val);
                    else
                        Y[(size_t)row * OSTRIDE + col] = f2bf(val);
                }
            }
        }
    }
}

// ---------------- agg1: feature-chunked, XCD-pinned ----------------
// msg chunk-major: 8 arrays [n][16 feats] (3.2MB each, L2-resident per XCD).
// chunk = blockIdx&7 (perf-only pinning). Per node: 32 edge-slots x 2 lanes x 16B,
// 2 gathers in flight, 5-stage shuffle reduce, lanes 0/1 write 64B output sub-row.
__global__ __launch_bounds__(256, 8) void k_agg_w128c(
        const uint4* __restrict__ msg, const float* __restrict__ dinv,
        const int* __restrict__ rs, const int* __restrict__ deg,
        const int* __restrict__ csr, const float* __restrict__ bias,
        float* __restrict__ out, int n) {
    int c = blockIdx.x & 7;
    int gw = (blockIdx.x >> 3) * 4 + (threadIdx.x >> 6);  // 0..(gridDim/8*4)-1
    int nw = (gridDim.x >> 3) * 4;
    int lane = threadIdx.x & 63;
    int slot = lane >> 1, q = lane & 1;
    const uint4* mc = msg + (size_t)c * n * 2;  // chunk base
    for (int v = gw; v < n; v += nw) {
        int start = rs[v];
        int cnt = deg[v];
        float dv = dinv[v];
        float acc[8] = {0.f, 0.f, 0.f, 0.f, 0.f, 0.f, 0.f, 0.f};
        int i = slot;
        for (; i + 32 < cnt; i += 64) {  // 2 gathers in flight
            int s0 = csr[start + i];
            int s1 = csr[start + i + 32];
            uint4 m0 = mc[(size_t)s0 * 2 + q];
            uint4 m1 = mc[(size_t)s1 * 2 + q];
            acc8(acc, m0);
            acc8(acc, m1);
        }
        if (i < cnt) {
            int s = csr[start + i];
            uint4 m = mc[(size_t)s * 2 + q];
            acc8(acc, m);
        }
#pragma unroll
        for (int j = 0; j < 8; j++) {
            acc[j] += __shfl_xor(acc[j], 2);
            acc[j] += __shfl_xor(acc[j], 4);
            acc[j] += __shfl_xor(acc[j], 8);
            acc[j] += __shfl_xor(acc[j], 16);
            acc[j] += __shfl_xor(acc[j], 32);
        }
        if (lane < 2) {
            uint4 mself = mc[(size_t)v * 2 + q];
            float o[8];
            o[0] = acc[0] + bf_lo(mself.x); o[1] = acc[1] + bf_hi(mself.x);
            o[2] = acc[2] + bf_lo(mself.y); o[3] = acc[3] + bf_hi(mself.y);
            o[4] = acc[4] + bf_lo(mself.z); o[5] = acc[5] + bf_hi(mself.z);
            o[6] = acc[6] + bf_lo(mself.w); o[7] = acc[7] + bf_hi(mself.w);
            float r[8];
#pragma unroll
            for (int j = 0; j < 8; j++)
                r[j] = fmaxf(dv * o[j] + bias[c * 16 + 8 * q + j], 0.f);
            // 64B-aligned contiguous across lanes 0/1 -> nt safe (full sector)
            float4v* op = (float4v*)(out + (size_t)v * 128 + c * 16 + 8 * q);
            __builtin_nontemporal_store((float4v){r[0], r[1], r[2], r[3]}, op);
            __builtin_nontemporal_store((float4v){r[4], r[5], r[6], r[7]}, op + 1);
        }
    }
}

// ---------------- agg2: persistent, one node per wave, 7 slots x 9 lanes, 3-in-flight ----------------
__global__ __launch_bounds__(256, 8) void k_agg_w72(
        const uint4* __restrict__ msg, const float* __restrict__ dinv,
        const int* __restrict__ rs, const int* __restrict__ deg,
        const int* __restrict__ csr, const float* __restrict__ bias,
        float* __restrict__ out, int n) {
    int lane = threadIdx.x & 63;
    int slot = lane / 9;
    int q = lane - slot * 9;
    bool active = lane < 63;
    int wid = blockIdx.x * 4 + (threadIdx.x >> 6);
    int nw = gridDim.x * 4;
    for (int v = wid; v < n; v += nw) {
        int start = rs[v];
        int cnt = deg[v];
        float dv = dinv[v];
        float acc[8] = {0.f, 0.f, 0.f, 0.f, 0.f, 0.f, 0.f, 0.f};
        uint4 mself = make_uint4(0, 0, 0, 0);
        if (active) {
            mself = msg[(size_t)v * 9 + q];
            int i = slot;
            for (; i + 14 < cnt; i += 21) {  // 3 gathers in flight per slot
                int s0 = csr[start + i];
                int s1 = csr[start + i + 7];
                int s2 = csr[start + i + 14];
                uint4 m0 = msg[(size_t)s0 * 9 + q];
                uint4 m1 = msg[(size_t)s1 * 9 + q];
                uint4 m2 = msg[(size_t)s2 * 9 + q];
                acc8(acc, m0);
                acc8(acc, m1);
                acc8(acc, m2);
            }
            for (; i + 7 < cnt; i += 14) {
                int s0 = csr[start + i];
                int s1 = csr[start + i + 7];
                uint4 m0 = msg[(size_t)s0 * 9 + q];
                uint4 m1 = msg[(size_t)s1 * 9 + q];
                acc8(acc, m0);
                acc8(acc, m1);
            }
            if (i < cnt) {
                int s = csr[start + i];
                uint4 m = msg[(size_t)s * 9 + q];
                acc8(acc, m);
            }
        }
#pragma unroll
        for (int j = 0; j < 8; j++) {
            float t27 = __shfl(acc[j], lane + 27);
            if (lane < 27) acc[j] += t27;
        }
#pragma unroll
        for (int j = 0; j < 8; j++) {
            float t54 = __shfl(acc[j], lane + 54);
            float t9  = __shfl(acc[j], lane + 9);
            float t18 = __shfl(acc[j], lane + 18);
            if (lane < 9) acc[j] += t54 + t9 + t18;
        }
        if (lane < 9) {
            float o[8];
            o[0] = acc[0] + bf_lo(mself.x); o[1] = acc[1] + bf_hi(mself.x);
            o[2] = acc[2] + bf_lo(mself.y); o[3] = acc[3] + bf_hi(mself.y);
            o[4] = acc[4] + bf_lo(mself.z); o[5] = acc[5] + bf_hi(mself.z);
            o[6] = acc[6] + bf_lo(mself.w); o[7] = acc[7] + bf_hi(mself.w);
            float* orow = out + (size_t)v * 70 + 8 * q;
#pragma unroll
            for (int jj = 0; jj < 4; jj++) {
                int f = 8 * q + 2 * jj;
                if (f < 70) {
                    float2 st = make_float2(dv * o[2 * jj] + bias[f],
                                            dv * o[2 * jj + 1] + bias[f + 1]);
                    *(float2*)(orow + 2 * jj) = st;  // cached: L2 coalesces partial lines
                }
            }
        }
    }
}

static inline size_t alignup(size_t x) { return (x + 255) & ~(size_t)255; }

extern "C" void kernel_launch(void* const* d_in, const int* in_sizes, int n_in,
                              void* d_out, int out_size, void* d_ws, size_t ws_size,
                              hipStream_t stream) {
    const float* x = (const float*)d_in[0];
    const int* edge = (const int*)d_in[1];
    const float* W1 = (const float*)d_in[2];
    const float* b1 = (const float*)d_in[3];
    const float* W2 = (const float*)d_in[4];
    const float* b2 = (const float*)d_in[5];

    const int N = in_sizes[0] / 128;
    const int E = in_sizes[1] / 2;
    const int* src = edge;
    const int* dst = edge + E;
    const int nb = (N + 255) >> BSH;

    char* w = (char*)d_ws;
    int* deg = (int*)w;              w += alignup((size_t)N * 4);
    float* dinv = (float*)w;         w += alignup((size_t)N * 4);
    int* rs = (int*)w;               w += alignup((size_t)N * 4);
    int* bhist = (int*)w;            w += alignup(4096);
    int* bbase = (int*)w;            w += alignup(4096);
    int* bwcur = (int*)w;            w += alignup(4096);
    int* csr = (int*)w;              w += alignup((size_t)E * 4);
    unsigned short* msg1 = (unsigned short*)w; w += alignup((size_t)N * 128 * 2);
    unsigned short* msg2 = (unsigned short*)w; w += alignup((size_t)N * 72 * 2);
    unsigned short* w1th = (unsigned short*)w; w += alignup(128 * 128 * 2);
    unsigned short* w1tl = (unsigned short*)w; w += alignup(128 * 128 * 2);
    unsigned short* w2th = (unsigned short*)w; w += alignup(80 * 128 * 2);
    unsigned short* w2tl = (unsigned short*)w; w += alignup(80 * 128 * 2);
    float* h = (float*)w;            w += alignup((size_t)N * 128 * 4);
    unsigned long long* tmp = (unsigned long long*)h;  // aliases h (disjoint in time)

    // ---- W pre-split (independent of graph) ----
    k_prep_w<<<(128 * 128 + 255) / 256, 256, 0, stream>>>(W1, w1th, w1tl, 128, 128);
    k_prep_w<<<(80 * 128 + 255) / 256, 256, 0, stream>>>(W2, w2th, w2tl, 70, 80);

    // ---- CSR build ----
    hipMemsetAsync(bhist, 0, (size_t)(nb + 1) * 4, stream);
    k_bucket_hist<<<256, 256, 0, stream>>>(dst, bhist, E, nb);
    k_bucket_scan<<<1, 512, 0, stream>>>(bhist, bbase, bwcur, nb, E);
    k_bucket_scatter<<<(E + BCHUNK - 1) / BCHUNK, 256, 0, stream>>>(src, dst, bwcur, tmp, E, nb);
    k_bucket_finalize<<<nb, 256, 0, stream>>>(tmp, bbase, deg, dinv, rs, csr, N);

    int gblocks = (N + 63) / 64;

    // Layer 1: msg1 = bf16(dinv * (x @ W1)) chunk-major [8][N][16] ; agg -> h [N,128] fp32
    k_gemm_mfma<128, 128, 8, true><<<gblocks, 256, 0, stream>>>(x, w1th, w1tl, dinv, msg1, N);
    k_agg_w128c<<<2048, 256, 0, stream>>>((const uint4*)msg1, dinv, rs, deg, csr, b1, h, N);

    // Layer 2: msg2 = bf16(dinv * (h @ W2)) [N,72 pad] ; agg -> d_out [N,70] (bias)
    k_gemm_mfma<70, 72, 5, false><<<gblocks, 256, 0, stream>>>(h, w2th, w2tl, dinv, msg2, N);
    k_agg_w72<<<2048, 256, 0, stream>>>((const uint4*)msg2, dinv, rs, deg, csr, b2,
                                        (float*)d_out, N);
}

// Round 4
// 454.465 us; speedup vs baseline: 1.4608x; 1.4608x over previous
//
#include <hip/hip_runtime.h>
#include <hip/hip_bf16.h>

// GCN 2-layer. msg[s] = dinv[s] * (x@W)[s] stored in bf16 (dinv folded at GEMM epilogue).
// out[v] = dinv[v] * (sum_{e:dst=v} msg[src] + msg[v]) + b ; layer1 relu.
// CSR build: bucketed 2-phase counting sort (bucket = dst>>8).
// GEMMs: MFMA 16x16x32 bf16, 2-term split (~fp32 accuracy), chunk-major epilogue.
// R8 lesson: nt stores only on >=64B-contiguous sectors; nt loads on one-touch streams ok.
// R9 lesson: flat agg is traffic-bound at the 8-XCD compulsory floor (193MB, 3.8TB/s).
// R10 lesson: chunk-major msg + blockIdx%8 XCD pinning IS L2-resident (FETCH 193->46MB,
//   pinning confirmed) BUT the wave-per-node 5-stage shuffle reduce x 8 chunk-visits
//   serialized on the DS pipe (40 DS ops x 800k visits -> 383us). Structure, not traffic.
// R11: keep chunking; kill ALL shuffles. 2 lanes per node x 32 nodes per wave; each lane
//   owns 8 of the node's 16 chunk-feats and serially walks the edge list (unroll 4).
//   Zero cross-lane ops, direct per-lane epilogue store. Same for layer 2 via 5 padded
//   chunks [5][N][16] and chunk map c=(blockIdx&7)*5/8 (every XCD still sees one 3.2MB
//   chunk; chunks with 2 block-groups split the node range).

#define BSH 8
#define BCHUNK 8192

typedef __attribute__((ext_vector_type(8))) short short8;
typedef __attribute__((ext_vector_type(4))) float float4v;
typedef __attribute__((ext_vector_type(2))) float float2v;

__device__ __forceinline__ float bf_lo(unsigned u) { return __uint_as_float(u << 16); }
__device__ __forceinline__ float bf_hi(unsigned u) { return __uint_as_float(u & 0xffff0000u); }
__device__ __forceinline__ float bf2f(unsigned short h) {
    return __uint_as_float((unsigned)h << 16);
}
__device__ __forceinline__ unsigned short f2bf(float f) {
    unsigned u = __float_as_uint(f);
    u += 0x7fff + ((u >> 16) & 1);  // round-to-nearest-even
    return (unsigned short)(u >> 16);
}
__device__ __forceinline__ void acc8(float* acc, uint4 m) {
    acc[0] += bf_lo(m.x); acc[1] += bf_hi(m.x);
    acc[2] += bf_lo(m.y); acc[3] += bf_hi(m.y);
    acc[4] += bf_lo(m.z); acc[5] += bf_hi(m.z);
    acc[6] += bf_lo(m.w); acc[7] += bf_hi(m.w);
}

// ---------------- CSR build ----------------

__global__ void k_bucket_hist(const int* __restrict__ dst, int* __restrict__ bhist,
                              int E, int nb) {
    __shared__ int h[512];
    int t = threadIdx.x;
    for (int j = t; j < nb; j += blockDim.x) h[j] = 0;
    __syncthreads();
    int i = blockIdx.x * blockDim.x + t;
    int stride = gridDim.x * blockDim.x;
    for (; i < E; i += stride) atomicAdd(&h[dst[i] >> BSH], 1);
    __syncthreads();
    for (int j = t; j < nb; j += blockDim.x) {
        int c = h[j];
        if (c) atomicAdd(&bhist[j], c);
    }
}

__global__ void k_bucket_scan(const int* __restrict__ bhist, int* __restrict__ bbase,
                              int* __restrict__ bwcur, int nb, int E) {
    __shared__ int s[512];
    int t = threadIdx.x;
    int v = (t < nb) ? bhist[t] : 0;
    s[t] = v;
    __syncthreads();
    for (int off = 1; off < 512; off <<= 1) {
        int add = (t >= off) ? s[t - off] : 0;
        __syncthreads();
        s[t] += add;
        __syncthreads();
    }
    if (t < nb) {
        int excl = s[t] - v;
        bbase[t] = excl;
        bwcur[t] = excl;
    }
    if (t == 0) bbase[nb] = E;
}

__global__ void k_bucket_scatter(const int* __restrict__ src, const int* __restrict__ dst,
                                 int* __restrict__ bwcur,
                                 unsigned long long* __restrict__ tmp, int E, int nb) {
    __shared__ int lh[512];
    __shared__ int lb[512];
    int t = threadIdx.x;
    for (int j = t; j < nb; j += 256) lh[j] = 0;
    __syncthreads();
    int e0 = blockIdx.x * BCHUNK;
    int e1 = min(E, e0 + BCHUNK);
    for (int e = e0 + t; e < e1; e += 256) atomicAdd(&lh[dst[e] >> BSH], 1);
    __syncthreads();
    for (int j = t; j < nb; j += 256) {
        int c = lh[j];
        lb[j] = c ? atomicAdd(&bwcur[j], c) : 0;
        lh[j] = 0;
    }
    __syncthreads();
    for (int e = e0 + t; e < e1; e += 256) {
        int d = dst[e];
        int b = d >> BSH;
        int o = atomicAdd(&lh[b], 1);
        tmp[lb[b] + o] = ((unsigned long long)(unsigned)d << 32) | (unsigned)src[e];
    }
}

__global__ void k_bucket_finalize(const unsigned long long* __restrict__ tmp,
                                  const int* __restrict__ bbase,
                                  int* __restrict__ deg, float* __restrict__ dinv,
                                  int* __restrict__ rs, int* __restrict__ csr, int N) {
    __shared__ int cnt[256];
    __shared__ int sc[256];
    int b = blockIdx.x;
    int t = threadIdx.x;
    int e0 = bbase[b], e1 = bbase[b + 1];
    cnt[t] = 0;
    __syncthreads();
    for (int e = e0 + t; e < e1; e += 256) {
        int d = (int)(tmp[e] >> 32);
        atomicAdd(&cnt[d & 255], 1);
    }
    __syncthreads();
    int c = cnt[t];
    sc[t] = c;
    __syncthreads();
    for (int off = 1; off < 256; off <<= 1) {
        int add = (t >= off) ? sc[t - off] : 0;
        __syncthreads();
        sc[t] += add;
        __syncthreads();
    }
    int excl = sc[t] - c;
    __syncthreads();
    sc[t] = excl;
    int node = (b << BSH) + t;
    if (node < N) {
        deg[node] = c;
        dinv[node] = rsqrtf((float)(c + 1));
        rs[node] = e0 + excl;
    }
    cnt[t] = 0;
    __syncthreads();
    for (int e = e0 + t; e < e1; e += 256) {
        unsigned long long p = tmp[e];
        int j = ((int)(p >> 32)) & 255;
        int o = atomicAdd(&cnt[j], 1);
        csr[e0 + sc[j] + o] = (int)(p & 0xffffffffu);
    }
}

// ---------------- W pre-split: Wt_h/Wt_l[col][k] bf16, cols >= DOUT zeroed ----------------
__global__ void k_prep_w(const float* __restrict__ W, unsigned short* __restrict__ Wth,
                         unsigned short* __restrict__ Wtl, int DOUT, int COLS) {
    int i = blockIdx.x * blockDim.x + threadIdx.x;
    if (i >= COLS * 128) return;
    int col = i % COLS;
    int k = i / COLS;
    float w = (col < DOUT) ? W[k * DOUT + col] : 0.f;
    unsigned short h = f2bf(w);
    Wth[(size_t)col * 128 + k] = h;
    Wtl[(size_t)col * 128 + k] = f2bf(w - bf2f(h));
}

// ---------------- MFMA GEMM (split-bf16, ~fp32 accuracy) ----------------
// Y chunk-major: Y[((col>>4)*n + row)*16 + (col&15)], cols >= DOUT written as 0.
template <int DOUT, int NCOLS, int NT>
__global__ __launch_bounds__(256, 3) void k_gemm_mfma(
        const float* __restrict__ X, const unsigned short* __restrict__ Wth,
        const unsigned short* __restrict__ Wtl,
        const float* __restrict__ dinv, unsigned short* __restrict__ Y, int n) {
    __shared__ short xs_h[64][136];
    __shared__ short xs_l[64][136];
    int t = threadIdx.x;
    int lane = t & 63, wave = t >> 6;
    int m16 = lane & 15, quad = lane >> 4;
    int r0 = blockIdx.x * 64;

    short8 bh[2][4], bl[2][4];
    int nt0 = wave, nt1 = wave + 4;
#pragma unroll
    for (int i = 0; i < 2; i++) {
        int nt = i ? nt1 : nt0;
        if (nt >= NT) continue;
        int col = nt * 16 + m16;  // < NT*16 <= padded Wt cols
#pragma unroll
        for (int kc = 0; kc < 4; kc++) {
            bh[i][kc] = *(const short8*)&Wth[(size_t)col * 128 + kc * 32 + quad * 8];
            bl[i][kc] = *(const short8*)&Wtl[(size_t)col * 128 + kc * 32 + quad * 8];
        }
    }

    for (int p = t; p < 64 * 64; p += 256) {
        int row = p >> 6;
        int kk = p & 63;
        int gr = r0 + row;
        if (gr >= n) gr = n - 1;
        float2v xv = __builtin_nontemporal_load(
            (const float2v*)(X + (size_t)gr * 128 + 2 * kk));
        unsigned short h0 = f2bf(xv.x), h1 = f2bf(xv.y);
        unsigned short l0 = f2bf(xv.x - bf2f(h0)), l1 = f2bf(xv.y - bf2f(h1));
        *(unsigned*)&xs_h[row][2 * kk] = (unsigned)h0 | ((unsigned)h1 << 16);
        *(unsigned*)&xs_l[row][2 * kk] = (unsigned)l0 | ((unsigned)l1 << 16);
    }
    __syncthreads();

    float4v acc[2][4];
#pragma unroll
    for (int i = 0; i < 2; i++)
#pragma unroll
        for (int ms = 0; ms < 4; ms++) acc[i][ms] = (float4v){0.f, 0.f, 0.f, 0.f};

#pragma unroll
    for (int kc = 0; kc < 4; kc++) {
#pragma unroll
        for (int ms = 0; ms < 4; ms++) {
            short8 ah = *(short8*)&xs_h[ms * 16 + m16][kc * 32 + quad * 8];
            short8 al = *(short8*)&xs_l[ms * 16 + m16][kc * 32 + quad * 8];
#pragma unroll
            for (int i = 0; i < 2; i++) {
                int nt = i ? nt1 : nt0;
                if (nt >= NT) continue;
                acc[i][ms] = __builtin_amdgcn_mfma_f32_16x16x32_bf16(ah, bh[i][kc], acc[i][ms], 0, 0, 0);
                acc[i][ms] = __builtin_amdgcn_mfma_f32_16x16x32_bf16(al, bh[i][kc], acc[i][ms], 0, 0, 0);
                acc[i][ms] = __builtin_amdgcn_mfma_f32_16x16x32_bf16(ah, bl[i][kc], acc[i][ms], 0, 0, 0);
            }
        }
    }

#pragma unroll
    for (int i = 0; i < 2; i++) {
        int nt = i ? nt1 : nt0;
        if (nt >= NT) continue;
        int col = nt * 16 + m16;
        if (col >= NCOLS) continue;
#pragma unroll
        for (int ms = 0; ms < 4; ms++) {
#pragma unroll
            for (int r = 0; r < 4; r++) {
                int row = r0 + ms * 16 + quad * 4 + r;
                if (row < n) {
                    float val = (col < DOUT) ? acc[i][ms][r] * dinv[row] : 0.f;
                    Y[((size_t)nt * n + row) * 16 + m16] = f2bf(val);
                }
            }
        }
    }
}

// ---------------- chunked agg: 2 lanes/node, 32 nodes/wave, zero shuffles ----------------
// msg chunk-major: [NCH][n][16 feats] bf16 (32B per node-chunk; 3.2MB per chunk).
// Chunk pinned to XCD via blockIdx&7 (NCH=8: identity; NCH=5: c=k*5/8, chunks with
// 2 block-groups split the node range). Each lane owns 8 feats of its node and
// serially walks the edge list (unroll 4); epilogue stores directly.
template <int NCH, bool RELU, int DOUT, int OSTRIDE>
__global__ __launch_bounds__(256, 8) void k_agg_chunk(
        const uint4* __restrict__ msg, const float* __restrict__ dinv,
        const int* __restrict__ rs, const int* __restrict__ deg,
        const int* __restrict__ csr, const float* __restrict__ bias,
        float* __restrict__ out, int n) {
    int k = blockIdx.x & 7;
    int c, iw, ng;
    if (NCH == 8) {
        c = k; iw = 0; ng = 1;
    } else {  // NCH == 5: k -> chunk {0,0,1,1,2,3,3,4}
        const int cm[8] = {0, 0, 1, 1, 2, 3, 3, 4};
        const int im[8] = {0, 1, 0, 1, 0, 0, 1, 0};
        const int nbk[5] = {2, 2, 1, 2, 1};
        c = cm[k]; iw = im[k]; ng = nbk[c];
    }
    int bpg = gridDim.x >> 3;  // blocks per k-group
    int wid = (iw * bpg + (blockIdx.x >> 3)) * 4 + (threadIdx.x >> 6);
    int nw = ng * bpg * 4;
    int lane = threadIdx.x & 63;
    int pr = lane >> 1;  // node-pair index 0..31
    int q = lane & 1;    // feature half
    const uint4* mc = msg + (size_t)c * n * 2;
    for (int base = wid * 32; base < n; base += nw * 32) {
        int v = base + pr;
        bool valid = v < n;
        int start = 0, cnt = 0;
        float dv = 0.f;
        if (valid) { start = rs[v]; cnt = deg[v]; dv = dinv[v]; }
        float acc[8] = {0.f, 0.f, 0.f, 0.f, 0.f, 0.f, 0.f, 0.f};
        int i = 0;
        for (; i + 3 < cnt; i += 4) {  // 4 gathers in flight per lane
            int s0 = csr[start + i];
            int s1 = csr[start + i + 1];
            int s2 = csr[start + i + 2];
            int s3 = csr[start + i + 3];
            uint4 m0 = mc[(size_t)s0 * 2 + q];
            uint4 m1 = mc[(size_t)s1 * 2 + q];
            uint4 m2 = mc[(size_t)s2 * 2 + q];
            uint4 m3 = mc[(size_t)s3 * 2 + q];
            acc8(acc, m0);
            acc8(acc, m1);
            acc8(acc, m2);
            acc8(acc, m3);
        }
        for (; i < cnt; i++) {
            uint4 m = mc[(size_t)csr[start + i] * 2 + q];
            acc8(acc, m);
        }
        if (valid) {
            uint4 ms = mc[(size_t)v * 2 + q];
            float o[8];
            o[0] = acc[0] + bf_lo(ms.x); o[1] = acc[1] + bf_hi(ms.x);
            o[2] = acc[2] + bf_lo(ms.y); o[3] = acc[3] + bf_hi(ms.y);
            o[4] = acc[4] + bf_lo(ms.z); o[5] = acc[5] + bf_hi(ms.z);
            o[6] = acc[6] + bf_lo(ms.w); o[7] = acc[7] + bf_hi(ms.w);
            int f0 = c * 16 + 8 * q;
            float r[8];
#pragma unroll
            for (int j = 0; j < 8; j++) {
                float b = (f0 + j < DOUT) ? bias[f0 + j] : 0.f;
                float val = dv * o[j] + b;
                r[j] = RELU ? fmaxf(val, 0.f) : val;
            }
            if (OSTRIDE == 128) {
                // 32B-aligned, 64B/node across the lane pair: nt-safe full sectors
                float4v* op = (float4v*)(out + (size_t)v * OSTRIDE + f0);
                __builtin_nontemporal_store((float4v){r[0], r[1], r[2], r[3]}, op);
                __builtin_nontemporal_store((float4v){r[4], r[5], r[6], r[7]}, op + 1);
            } else {
#pragma unroll
                for (int jj = 0; jj < 4; jj++) {
                    int f = f0 + 2 * jj;
                    if (f < DOUT) {  // DOUT even => f+1 < DOUT too
                        float2 st = make_float2(r[2 * jj], r[2 * jj + 1]);
                        *(float2*)(out + (size_t)v * OSTRIDE + f) = st;  // cached
                    }
                }
            }
        }
    }
}

static inline size_t alignup(size_t x) { return (x + 255) & ~(size_t)255; }

extern "C" void kernel_launch(void* const* d_in, const int* in_sizes, int n_in,
                              void* d_out, int out_size, void* d_ws, size_t ws_size,
                              hipStream_t stream) {
    const float* x = (const float*)d_in[0];
    const int* edge = (const int*)d_in[1];
    const float* W1 = (const float*)d_in[2];
    const float* b1 = (const float*)d_in[3];
    const float* W2 = (const float*)d_in[4];
    const float* b2 = (const float*)d_in[5];

    const int N = in_sizes[0] / 128;
    const int E = in_sizes[1] / 2;
    const int* src = edge;
    const int* dst = edge + E;
    const int nb = (N + 255) >> BSH;

    char* w = (char*)d_ws;
    int* deg = (int*)w;              w += alignup((size_t)N * 4);
    float* dinv = (float*)w;         w += alignup((size_t)N * 4);
    int* rs = (int*)w;               w += alignup((size_t)N * 4);
    int* bhist = (int*)w;            w += alignup(4096);
    int* bbase = (int*)w;            w += alignup(4096);
    int* bwcur = (int*)w;            w += alignup(4096);
    int* csr = (int*)w;              w += alignup((size_t)E * 4);
    unsigned short* msg1 = (unsigned short*)w; w += alignup((size_t)N * 128 * 2);
    unsigned short* msg2 = (unsigned short*)w; w += alignup((size_t)N * 80 * 2);
    unsigned short* w1th = (unsigned short*)w; w += alignup(128 * 128 * 2);
    unsigned short* w1tl = (unsigned short*)w; w += alignup(128 * 128 * 2);
    unsigned short* w2th = (unsigned short*)w; w += alignup(80 * 128 * 2);
    unsigned short* w2tl = (unsigned short*)w; w += alignup(80 * 128 * 2);
    float* h = (float*)w;            w += alignup((size_t)N * 128 * 4);
    unsigned long long* tmp = (unsigned long long*)h;  // aliases h (disjoint in time)

    // ---- W pre-split (independent of graph) ----
    k_prep_w<<<(128 * 128 + 255) / 256, 256, 0, stream>>>(W1, w1th, w1tl, 128, 128);
    k_prep_w<<<(80 * 128 + 255) / 256, 256, 0, stream>>>(W2, w2th, w2tl, 70, 80);

    // ---- CSR build ----
    hipMemsetAsync(bhist, 0, (size_t)(nb + 1) * 4, stream);
    k_bucket_hist<<<256, 256, 0, stream>>>(dst, bhist, E, nb);
    k_bucket_scan<<<1, 512, 0, stream>>>(bhist, bbase, bwcur, nb, E);
    k_bucket_scatter<<<(E + BCHUNK - 1) / BCHUNK, 256, 0, stream>>>(src, dst, bwcur, tmp, E, nb);
    k_bucket_finalize<<<nb, 256, 0, stream>>>(tmp, bbase, deg, dinv, rs, csr, N);

    int gblocks = (N + 63) / 64;

    // Layer 1: msg1 chunk-major [8][N][16] bf16 ; agg -> h [N,128] fp32 (bias+relu)
    k_gemm_mfma<128, 128, 8><<<gblocks, 256, 0, stream>>>(x, w1th, w1tl, dinv, msg1, N);
    k_agg_chunk<8, true, 128, 128><<<2048, 256, 0, stream>>>(
        (const uint4*)msg1, dinv, rs, deg, csr, b1, h, N);

    // Layer 2: msg2 chunk-major [5][N][16] bf16 (padded) ; agg -> d_out [N,70] (bias)
    k_gemm_mfma<70, 80, 5><<<gblocks, 256, 0, stream>>>(h, w2th, w2tl, dinv, msg2, N);
    k_agg_chunk<5, false, 70, 70><<<2048, 256, 0, stream>>>(
        (const uint4*)msg2, dinv, rs, deg, csr, b2, (float*)d_out, N);
}

// Round 5
// 348.034 us; speedup vs baseline: 1.9076x; 1.3058x over previous
//
#include <hip/hip_runtime.h>
#include <hip/hip_bf16.h>

// GCN 2-layer. msg[s] = dinv[s] * (x@W)[s] stored in bf16 (dinv folded at GEMM epilogue).
// out[v] = dinv[v] * (sum_{e:dst=v} msg[src] + msg[v]) + b ; layer1 relu.
// GEMMs: MFMA 16x16x32 bf16, 2-term split (~fp32 accuracy), x tile in LDS.
// Aggregation: persistent grid-stride, one node per wave, shuffle reduce at END only.
// --- Session ledger ---
// R7: never fuse the latency-bound gather into an LDS-heavy MFMA kernel (occupancy).
// R8: nt stores only on >=64B-contiguous sectors (8B scattered nt = 4x write amp).
//     nt loads on one-touch streams: neutral, kept.
// R9: flat agg is TRAFFIC-bound, not latency-bound (deeper MLP: zero delta).
//     FETCH 193MB ~= 8 XCDs x 25.6MB msg1 = per-XCD L2 compulsory floor.
// R10: chunk-major msg + blockIdx%8 XCD pinning IS L2-resident (FETCH 193->46MB,
//     pinning real) BUT wave-per-node shuffle reduce x8 visits = DS-pipe bound (383us).
// R11: chunked + per-lane serial edge walk = csr transaction + divergence bound (117us).
//     => chunked agg structurally dominated; flat agg 66us is the proven floor. REVERTED.
// R12: trim the invisible ~240us remainder: CSR build now 2 kernels (direct scatter
//     with per-bucket CAP slack, no hist/no scan), 1 merged prep_w, float4 gemm staging.

#define BSH 8
#define BCHUNK 8192
#define BCAP 8192  // tmp/csr slots per bucket (mean 4092, sigma 64 -> 64-sigma slack)

typedef __attribute__((ext_vector_type(8))) short short8;
typedef __attribute__((ext_vector_type(4))) float float4v;
typedef __attribute__((ext_vector_type(2))) float float2v;

__device__ __forceinline__ float bf_lo(unsigned u) { return __uint_as_float(u << 16); }
__device__ __forceinline__ float bf_hi(unsigned u) { return __uint_as_float(u & 0xffff0000u); }
__device__ __forceinline__ float bf2f(unsigned short h) {
    return __uint_as_float((unsigned)h << 16);
}
__device__ __forceinline__ unsigned short f2bf(float f) {
    unsigned u = __float_as_uint(f);
    u += 0x7fff + ((u >> 16) & 1);  // round-to-nearest-even
    return (unsigned short)(u >> 16);
}
__device__ __forceinline__ void acc8(float* acc, uint4 m) {
    acc[0] += bf_lo(m.x); acc[1] += bf_hi(m.x);
    acc[2] += bf_lo(m.y); acc[3] += bf_hi(m.y);
    acc[4] += bf_lo(m.z); acc[5] += bf_hi(m.z);
    acc[6] += bf_lo(m.w); acc[7] += bf_hi(m.w);
}

// ---------------- CSR build (2 kernels) ----------------
// Scatter: per-block LDS histogram -> one global cursor reservation per touched bucket
// -> scatter into bucket-strided tmp[b*BCAP + off]. No global hist, no scan.
__global__ void k_bucket_scatter(const int* __restrict__ src, const int* __restrict__ dst,
                                 int* __restrict__ bwcur,
                                 unsigned long long* __restrict__ tmp, int E, int nb) {
    __shared__ int lh[512];
    __shared__ int lb[512];
    int t = threadIdx.x;
    for (int j = t; j < nb; j += 256) lh[j] = 0;
    __syncthreads();
    int e0 = blockIdx.x * BCHUNK;
    int e1 = min(E, e0 + BCHUNK);
    for (int e = e0 + t; e < e1; e += 256) atomicAdd(&lh[dst[e] >> BSH], 1);
    __syncthreads();
    for (int j = t; j < nb; j += 256) {
        int c = lh[j];
        lb[j] = c ? atomicAdd(&bwcur[j], c) : 0;
        lh[j] = 0;
    }
    __syncthreads();
    for (int e = e0 + t; e < e1; e += 256) {
        int d = dst[e];
        int b = d >> BSH;
        int o = atomicAdd(&lh[b], 1);
        int pos = lb[b] + o;
        if (pos < BCAP)  // clamp: memory-safe even if a bucket overflows
            tmp[(size_t)b * BCAP + pos] =
                ((unsigned long long)(unsigned)d << 32) | (unsigned)src[e];
    }
}

__global__ void k_bucket_finalize(const unsigned long long* __restrict__ tmp,
                                  const int* __restrict__ bwcur,
                                  int* __restrict__ deg, float* __restrict__ dinv,
                                  int* __restrict__ rs, int* __restrict__ csr, int N) {
    __shared__ int cnt[256];
    __shared__ int sc[256];
    int b = blockIdx.x;
    int t = threadIdx.x;
    int e0 = b * BCAP;
    int e1 = e0 + min(bwcur[b], BCAP);
    cnt[t] = 0;
    __syncthreads();
    for (int e = e0 + t; e < e1; e += 256) {
        int d = (int)(tmp[e] >> 32);
        atomicAdd(&cnt[d & 255], 1);
    }
    __syncthreads();
    int c = cnt[t];
    sc[t] = c;
    __syncthreads();
    for (int off = 1; off < 256; off <<= 1) {
        int add = (t >= off) ? sc[t - off] : 0;
        __syncthreads();
        sc[t] += add;
        __syncthreads();
    }
    int excl = sc[t] - c;
    __syncthreads();
    sc[t] = excl;
    int node = (b << BSH) + t;
    if (node < N) {
        deg[node] = c;
        dinv[node] = rsqrtf((float)(c + 1));
        rs[node] = e0 + excl;
    }
    cnt[t] = 0;
    __syncthreads();
    for (int e = e0 + t; e < e1; e += 256) {
        unsigned long long p = tmp[e];
        int j = ((int)(p >> 32)) & 255;
        int o = atomicAdd(&cnt[j], 1);
        csr[e0 + sc[j] + o] = (int)(p & 0xffffffffu);
    }
}

// ---------------- W pre-split (both layers, one launch) ----------------
__global__ void k_prep_w(const float* __restrict__ W1, const float* __restrict__ W2,
                         unsigned short* __restrict__ w1th, unsigned short* __restrict__ w1tl,
                         unsigned short* __restrict__ w2th, unsigned short* __restrict__ w2tl) {
    int i = blockIdx.x * blockDim.x + threadIdx.x;
    if (i < 128 * 128) {
        int col = i % 128, k = i / 128;
        float w = W1[k * 128 + col];
        unsigned short h = f2bf(w);
        w1th[(size_t)col * 128 + k] = h;
        w1tl[(size_t)col * 128 + k] = f2bf(w - bf2f(h));
    } else if (i < 128 * 128 + 80 * 128) {
        int j = i - 128 * 128;
        int col = j % 80, k = j / 80;
        float w = (col < 70) ? W2[k * 70 + col] : 0.f;
        unsigned short h = f2bf(w);
        w2th[(size_t)col * 128 + k] = h;
        w2tl[(size_t)col * 128 + k] = f2bf(w - bf2f(h));
    }
}

// ---------------- MFMA GEMM (split-bf16, ~fp32 accuracy) ----------------
// Y[r,c] = bf16(dinv[r] * (X@W)[r,c]). Block: 4 waves, 64 rows, K=128.
// B frags loaded as 16B vectors from pre-split Wt. X staged via float4 nt loads.
template <int DOUT, int OSTRIDE, int NT>
__global__ __launch_bounds__(256, 3) void k_gemm_mfma(
        const float* __restrict__ X, const unsigned short* __restrict__ Wth,
        const unsigned short* __restrict__ Wtl,
        const float* __restrict__ dinv, unsigned short* __restrict__ Y, int n) {
    __shared__ short xs_h[64][136];
    __shared__ short xs_l[64][136];
    int t = threadIdx.x;
    int lane = t & 63, wave = t >> 6;
    int m16 = lane & 15, quad = lane >> 4;
    int r0 = blockIdx.x * 64;

    short8 bh[2][4], bl[2][4];
    int nt0 = wave, nt1 = wave + 4;
#pragma unroll
    for (int i = 0; i < 2; i++) {
        int nt = i ? nt1 : nt0;
        if (nt >= NT) continue;
        int col = nt * 16 + m16;  // < NT*16 <= padded Wt cols
#pragma unroll
        for (int kc = 0; kc < 4; kc++) {
            bh[i][kc] = *(const short8*)&Wth[(size_t)col * 128 + kc * 32 + quad * 8];
            bl[i][kc] = *(const short8*)&Wtl[(size_t)col * 128 + kc * 32 + quad * 8];
        }
    }

    for (int p = t; p < 64 * 32; p += 256) {
        int row = p >> 5;
        int k4 = p & 31;
        int gr = r0 + row;
        if (gr >= n) gr = n - 1;
        float4v xv = __builtin_nontemporal_load(
            (const float4v*)(X + (size_t)gr * 128 + 4 * k4));
        unsigned short h0 = f2bf(xv.x), h1 = f2bf(xv.y);
        unsigned short h2 = f2bf(xv.z), h3 = f2bf(xv.w);
        unsigned short l0 = f2bf(xv.x - bf2f(h0)), l1 = f2bf(xv.y - bf2f(h1));
        unsigned short l2 = f2bf(xv.z - bf2f(h2)), l3 = f2bf(xv.w - bf2f(h3));
        *(uint2*)&xs_h[row][4 * k4] =
            make_uint2((unsigned)h0 | ((unsigned)h1 << 16), (unsigned)h2 | ((unsigned)h3 << 16));
        *(uint2*)&xs_l[row][4 * k4] =
            make_uint2((unsigned)l0 | ((unsigned)l1 << 16), (unsigned)l2 | ((unsigned)l3 << 16));
    }
    __syncthreads();

    float4v acc[2][4];
#pragma unroll
    for (int i = 0; i < 2; i++)
#pragma unroll
        for (int ms = 0; ms < 4; ms++) acc[i][ms] = (float4v){0.f, 0.f, 0.f, 0.f};

#pragma unroll
    for (int kc = 0; kc < 4; kc++) {
#pragma unroll
        for (int ms = 0; ms < 4; ms++) {
            short8 ah = *(short8*)&xs_h[ms * 16 + m16][kc * 32 + quad * 8];
            short8 al = *(short8*)&xs_l[ms * 16 + m16][kc * 32 + quad * 8];
#pragma unroll
            for (int i = 0; i < 2; i++) {
                int nt = i ? nt1 : nt0;
                if (nt >= NT) continue;
                acc[i][ms] = __builtin_amdgcn_mfma_f32_16x16x32_bf16(ah, bh[i][kc], acc[i][ms], 0, 0, 0);
                acc[i][ms] = __builtin_amdgcn_mfma_f32_16x16x32_bf16(al, bh[i][kc], acc[i][ms], 0, 0, 0);
                acc[i][ms] = __builtin_amdgcn_mfma_f32_16x16x32_bf16(ah, bl[i][kc], acc[i][ms], 0, 0, 0);
            }
        }
    }

#pragma unroll
    for (int i = 0; i < 2; i++) {
        int nt = i ? nt1 : nt0;
        if (nt >= NT) continue;
        int col = nt * 16 + m16;
        if (col >= OSTRIDE) continue;
#pragma unroll
        for (int ms = 0; ms < 4; ms++) {
#pragma unroll
            for (int r = 0; r < 4; r++) {
                int row = r0 + ms * 16 + quad * 4 + r;
                if (row < n) {
                    float val = (col < DOUT) ? acc[i][ms][r] * dinv[row] : 0.f;
                    Y[(size_t)row * OSTRIDE + col] = f2bf(val);
                }
            }
        }
    }
}

// ---------------- agg1: persistent, one node per wave, 4 slots x 4-in-flight ----------------
__global__ __launch_bounds__(256, 8) void k_agg_w128(
        const uint4* __restrict__ msg, const float* __restrict__ dinv,
        const int* __restrict__ rs, const int* __restrict__ deg,
        const int* __restrict__ csr, const float* __restrict__ bias,
        float* __restrict__ out, int n) {
    int lane = threadIdx.x & 63;
    int q = lane & 15;
    int slot = lane >> 4;
    int wid = blockIdx.x * 4 + (threadIdx.x >> 6);
    int nw = gridDim.x * 4;
    for (int v = wid; v < n; v += nw) {
        int start = rs[v];
        int cnt = deg[v];
        float dv = dinv[v];
        uint4 mself = msg[(size_t)v * 16 + q];
        float acc[8] = {0.f, 0.f, 0.f, 0.f, 0.f, 0.f, 0.f, 0.f};
        int i = slot;
        for (; i + 12 < cnt; i += 16) {  // 4 gathers in flight per slot
            int s0 = csr[start + i];
            int s1 = csr[start + i + 4];
            int s2 = csr[start + i + 8];
            int s3 = csr[start + i + 12];
            uint4 m0 = msg[(size_t)s0 * 16 + q];
            uint4 m1 = msg[(size_t)s1 * 16 + q];
            uint4 m2 = msg[(size_t)s2 * 16 + q];
            uint4 m3 = msg[(size_t)s3 * 16 + q];
            acc8(acc, m0);
            acc8(acc, m1);
            acc8(acc, m2);
            acc8(acc, m3);
        }
        for (; i + 4 < cnt; i += 8) {  // 2 in flight
            int s0 = csr[start + i];
            int s1 = csr[start + i + 4];
            uint4 m0 = msg[(size_t)s0 * 16 + q];
            uint4 m1 = msg[(size_t)s1 * 16 + q];
            acc8(acc, m0);
            acc8(acc, m1);
        }
        if (i < cnt) {
            int s = csr[start + i];
            uint4 m = msg[(size_t)s * 16 + q];
            acc8(acc, m);
        }
#pragma unroll
        for (int j = 0; j < 8; j++) acc[j] += __shfl_xor(acc[j], 32);
#pragma unroll
        for (int j = 0; j < 8; j++) acc[j] += __shfl_xor(acc[j], 16);
        if (slot == 0) {
            float o[8];
            o[0] = acc[0] + bf_lo(mself.x); o[1] = acc[1] + bf_hi(mself.x);
            o[2] = acc[2] + bf_lo(mself.y); o[3] = acc[3] + bf_hi(mself.y);
            o[4] = acc[4] + bf_lo(mself.z); o[5] = acc[5] + bf_hi(mself.z);
            o[6] = acc[6] + bf_lo(mself.w); o[7] = acc[7] + bf_hi(mself.w);
            float r[8];
#pragma unroll
            for (int j = 0; j < 8; j++) r[j] = fmaxf(dv * o[j] + bias[8 * q + j], 0.f);
            float4v* op = (float4v*)(out + (size_t)v * 128 + 8 * q);
            __builtin_nontemporal_store((float4v){r[0], r[1], r[2], r[3]}, op);
            __builtin_nontemporal_store((float4v){r[4], r[5], r[6], r[7]}, op + 1);
        }
    }
}

// ---------------- agg2: persistent, one node per wave, 7 slots x 9 lanes, 3-in-flight ----------------
__global__ __launch_bounds__(256, 8) void k_agg_w72(
        const uint4* __restrict__ msg, const float* __restrict__ dinv,
        const int* __restrict__ rs, const int* __restrict__ deg,
        const int* __restrict__ csr, const float* __restrict__ bias,
        float* __restrict__ out, int n) {
    int lane = threadIdx.x & 63;
    int slot = lane / 9;
    int q = lane - slot * 9;
    bool active = lane < 63;
    int wid = blockIdx.x * 4 + (threadIdx.x >> 6);
    int nw = gridDim.x * 4;
    for (int v = wid; v < n; v += nw) {
        int start = rs[v];
        int cnt = deg[v];
        float dv = dinv[v];
        float acc[8] = {0.f, 0.f, 0.f, 0.f, 0.f, 0.f, 0.f, 0.f};
        uint4 mself = make_uint4(0, 0, 0, 0);
        if (active) {
            mself = msg[(size_t)v * 9 + q];
            int i = slot;
            for (; i + 14 < cnt; i += 21) {  // 3 gathers in flight per slot
                int s0 = csr[start + i];
                int s1 = csr[start + i + 7];
                int s2 = csr[start + i + 14];
                uint4 m0 = msg[(size_t)s0 * 9 + q];
                uint4 m1 = msg[(size_t)s1 * 9 + q];
                uint4 m2 = msg[(size_t)s2 * 9 + q];
                acc8(acc, m0);
                acc8(acc, m1);
                acc8(acc, m2);
            }
            for (; i + 7 < cnt; i += 14) {
                int s0 = csr[start + i];
                int s1 = csr[start + i + 7];
                uint4 m0 = msg[(size_t)s0 * 9 + q];
                uint4 m1 = msg[(size_t)s1 * 9 + q];
                acc8(acc, m0);
                acc8(acc, m1);
            }
            if (i < cnt) {
                int s = csr[start + i];
                uint4 m = msg[(size_t)s * 9 + q];
                acc8(acc, m);
            }
        }
#pragma unroll
        for (int j = 0; j < 8; j++) {
            float t27 = __shfl(acc[j], lane + 27);
            if (lane < 27) acc[j] += t27;
        }
#pragma unroll
        for (int j = 0; j < 8; j++) {
            float t54 = __shfl(acc[j], lane + 54);
            float t9  = __shfl(acc[j], lane + 9);
            float t18 = __shfl(acc[j], lane + 18);
            if (lane < 9) acc[j] += t54 + t9 + t18;
        }
        if (lane < 9) {
            float o[8];
            o[0] = acc[0] + bf_lo(mself.x); o[1] = acc[1] + bf_hi(mself.x);
            o[2] = acc[2] + bf_lo(mself.y); o[3] = acc[3] + bf_hi(mself.y);
            o[4] = acc[4] + bf_lo(mself.z); o[5] = acc[5] + bf_hi(mself.z);
            o[6] = acc[6] + bf_lo(mself.w); o[7] = acc[7] + bf_hi(mself.w);
            float* orow = out + (size_t)v * 70 + 8 * q;
#pragma unroll
            for (int jj = 0; jj < 4; jj++) {
                int f = 8 * q + 2 * jj;
                if (f < 70) {
                    float2 st = make_float2(dv * o[2 * jj] + bias[f],
                                            dv * o[2 * jj + 1] + bias[f + 1]);
                    *(float2*)(orow + 2 * jj) = st;  // cached: L2 coalesces partial lines
                }
            }
        }
    }
}

static inline size_t alignup(size_t x) { return (x + 255) & ~(size_t)255; }

extern "C" void kernel_launch(void* const* d_in, const int* in_sizes, int n_in,
                              void* d_out, int out_size, void* d_ws, size_t ws_size,
                              hipStream_t stream) {
    const float* x = (const float*)d_in[0];
    const int* edge = (const int*)d_in[1];
    const float* W1 = (const float*)d_in[2];
    const float* b1 = (const float*)d_in[3];
    const float* W2 = (const float*)d_in[4];
    const float* b2 = (const float*)d_in[5];

    const int N = in_sizes[0] / 128;
    const int E = in_sizes[1] / 2;
    const int* src = edge;
    const int* dst = edge + E;
    const int nb = (N + 255) >> BSH;

    char* w = (char*)d_ws;
    int* deg = (int*)w;              w += alignup((size_t)N * 4);
    float* dinv = (float*)w;         w += alignup((size_t)N * 4);
    int* rs = (int*)w;               w += alignup((size_t)N * 4);
    int* bwcur = (int*)w;            w += alignup(4096);
    int* csr = (int*)w;              w += alignup((size_t)nb * BCAP * 4);
    unsigned short* msg1 = (unsigned short*)w; w += alignup((size_t)N * 128 * 2);
    unsigned short* msg2 = (unsigned short*)w; w += alignup((size_t)N * 72 * 2);
    unsigned short* w1th = (unsigned short*)w; w += alignup(128 * 128 * 2);
    unsigned short* w1tl = (unsigned short*)w; w += alignup(128 * 128 * 2);
    unsigned short* w2th = (unsigned short*)w; w += alignup(80 * 128 * 2);
    unsigned short* w2tl = (unsigned short*)w; w += alignup(80 * 128 * 2);
    float* h = (float*)w;            w += alignup((size_t)N * 128 * 4);
    unsigned long long* tmp = (unsigned long long*)h;  // aliases h (disjoint in time)

    // ---- W pre-split (one launch, both layers) ----
    k_prep_w<<<(128 * 128 + 80 * 128 + 255) / 256, 256, 0, stream>>>(
        W1, W2, w1th, w1tl, w2th, w2tl);

    // ---- CSR build: direct scatter with CAP slack (no hist, no scan) ----
    hipMemsetAsync(bwcur, 0, (size_t)nb * 4, stream);
    k_bucket_scatter<<<(E + BCHUNK - 1) / BCHUNK, 256, 0, stream>>>(src, dst, bwcur, tmp, E, nb);
    k_bucket_finalize<<<nb, 256, 0, stream>>>(tmp, bwcur, deg, dinv, rs, csr, N);

    int gblocks = (N + 63) / 64;

    // Layer 1: msg1 = bf16(dinv * (x @ W1)) [N,128] ; agg -> h [N,128] fp32 (bias+relu)
    k_gemm_mfma<128, 128, 8><<<gblocks, 256, 0, stream>>>(x, w1th, w1tl, dinv, msg1, N);
    k_agg_w128<<<2048, 256, 0, stream>>>((const uint4*)msg1, dinv, rs, deg, csr, b1, h, N);

    // Layer 2: msg2 = bf16(dinv * (h @ W2)) [N,72 pad] ; agg -> d_out [N,70] (bias)
    k_gemm_mfma<70, 72, 5><<<gblocks, 256, 0, stream>>>(h, w2th, w2tl, dinv, msg2, N);
    k_agg_w72<<<2048, 256, 0, stream>>>((const uint4*)msg2, dinv, rs, deg, csr, b2,
                                        (float*)d_out, N);
}